// Round 1
// baseline (2562.969 us; speedup 1.0000x reference)
//
#include <hip/hip_runtime.h>

#define B_ 512
#define T_ 64
#define CC_ 512
#define H_ 512
#define NS_ 26
#define NCLS_ 97
#define NEMB_ 256

typedef short bf16x8 __attribute__((ext_vector_type(8)));
typedef float f32x4 __attribute__((ext_vector_type(4)));

__device__ __forceinline__ unsigned short f2bf(float f) {
  union { float f; unsigned u; } v; v.f = f;
  unsigned r = v.u + 0x7fffu + ((v.u >> 16) & 1u);
  return (unsigned short)(r >> 16);
}
__device__ __forceinline__ float bf2f(unsigned short h) {
  union { unsigned u; float f; } v; v.u = ((unsigned)h) << 16;
  return v.f;
}
__device__ __forceinline__ float sigm_f(float x) { return 1.f / (1.f + __expf(-x)); }
__device__ __forceinline__ float tanh_f(float x) { return 1.f - 2.f / (1.f + __expf(2.f * x)); }

// ---------------- generic bf16 MFMA GEMM: out[M,N] = A[M,K] @ W[N,K]^T ----------------
// A can be split at column k0 between two sources (concat along K).
// Block: 256 thr = 4 waves; tile 64x64; wave w owns rows [16w,16w+16), all 64 cols.
template <bool HAS_A1, bool OUT_BF16, bool HAS_BIAS, bool HAS_ADD>
__global__ void gemm_bf16_k(const unsigned short* __restrict__ A0, long lda0, int k0,
                            const unsigned short* __restrict__ A1, long lda1,
                            const unsigned short* __restrict__ W,
                            const float* __restrict__ bias,
                            const float* __restrict__ addsrc, long ldadd,
                            float* __restrict__ outF, unsigned short* __restrict__ outB,
                            long ldo, int K, int Nvalid) {
  const int tid = threadIdx.x;
  const int w = tid >> 6;
  const int l = tid & 63;
  const int l15 = l & 15, lq = l >> 4;
  const long mrow = (long)blockIdx.y * 64 + w * 16 + l15;
  const int nbase = blockIdx.x * 64;
  const int kf = lq * 8;
  f32x4 acc[4] = {};
  for (int kt = 0; kt < K; kt += 32) {
    const int k = kt + kf;
    bf16x8 a;
    if (!HAS_A1 || k < k0) a = *(const bf16x8*)(A0 + mrow * lda0 + k);
    else                   a = *(const bf16x8*)(A1 + mrow * lda1 + (k - k0));
#pragma unroll
    for (int nb = 0; nb < 4; ++nb) {
      const bf16x8 b = *(const bf16x8*)(W + (long)(nbase + nb * 16 + l15) * K + k);
      acc[nb] = __builtin_amdgcn_mfma_f32_16x16x32_bf16(a, b, acc[nb], 0, 0, 0);
    }
  }
  const int r0 = w * 16 + lq * 4;
#pragma unroll
  for (int nb = 0; nb < 4; ++nb) {
    const int colg = nbase + nb * 16 + l15;
    if (colg >= Nvalid) continue;
#pragma unroll
    for (int r = 0; r < 4; ++r) {
      const long rowg = (long)blockIdx.y * 64 + r0 + r;
      float v = acc[nb][r];
      if (HAS_BIAS) v += bias[colg];
      if (HAS_ADD) v += addsrc[rowg * ldadd + colg];
      if (OUT_BF16) outB[rowg * ldo + colg] = f2bf(v);
      else          outF[rowg * ldo + colg] = v;
    }
  }
}

// ---------------- per-step attention: e -> softmax -> context ----------------
__global__ void attn_step_k(const unsigned short* __restrict__ Hproj,
                            const unsigned short* __restrict__ bH,
                            const float* __restrict__ hp_gh,
                            const float* __restrict__ w_score,
                            float* __restrict__ attn_map,
                            unsigned short* __restrict__ ctx, int s) {
  const int b = blockIdx.x, tid = threadIdx.x;
  __shared__ float hp_s[512];
  __shared__ float ws_s[512];
  __shared__ float e_s[64];
  hp_s[tid] = hp_gh[(long)b * 2560 + tid];
  hp_s[tid + 256] = hp_gh[(long)b * 2560 + tid + 256];
  ws_s[tid] = w_score[tid];
  ws_s[tid + 256] = w_score[tid + 256];
  __syncthreads();
  // e[t] = sum_h tanh(Hproj[b,t,h] + hp[h]) * w_score[h]; 4 threads per t
  const int t = tid >> 2, q = tid & 3;
  const unsigned short* hrow = Hproj + ((long)b * 64 + t) * 512 + q * 128;
  float acc = 0.f;
  for (int i = 0; i < 16; ++i) {
    const bf16x8 hv = *(const bf16x8*)(hrow + i * 8);
#pragma unroll
    for (int j = 0; j < 8; ++j) {
      const int h = q * 128 + i * 8 + j;
      const float x = bf2f((unsigned short)hv[j]) + hp_s[h];
      acc += tanh_f(x) * ws_s[h];
    }
  }
  acc += __shfl_xor(acc, 1);
  acc += __shfl_xor(acc, 2);
  if (q == 0) e_s[t] = acc;
  __syncthreads();
  if (tid < 64) {
    const float e = e_s[tid];
    float m = e;
    for (int off = 32; off; off >>= 1) m = fmaxf(m, __shfl_xor(m, off));
    const float p = __expf(e - m);
    float sum = p;
    for (int off = 32; off; off >>= 1) sum += __shfl_xor(sum, off);
    const float a = p / sum;
    e_s[tid] = a;
    attn_map[((long)b * 64 + tid) * 26 + s] = a;  // map[b,t,s]
  }
  __syncthreads();
  // context[b, 2*tid .. 2*tid+1] = sum_t alpha[t] * bH[b,t,c]
  float c0 = 0.f, c1 = 0.f;
  const unsigned short* bhb = bH + (long)b * 64 * 512 + 2 * tid;
  for (int t2 = 0; t2 < 64; ++t2) {
    const float a = e_s[t2];
    const unsigned pv = *(const unsigned*)(bhb + (long)t2 * 512);
    c0 += a * bf2f((unsigned short)(pv & 0xffffu));
    c1 += a * bf2f((unsigned short)(pv >> 16));
  }
  const unsigned packed = (unsigned)f2bf(c0) | ((unsigned)f2bf(c1) << 16);
  *(unsigned*)(ctx + (long)b * 512 + 2 * tid) = packed;
}

// ---------------- I_char from fz = [f1p | f2p | zp] ----------------
__global__ void ichar_step_k(const float* __restrict__ fz, unsigned short* __restrict__ Ichar,
                             float* __restrict__ Char_out, int s) {
  const int idx = blockIdx.x * 256 + threadIdx.x;  // B*H
  const int b = idx >> 9, j = idx & 511;
  const float* r = fz + (long)b * 1536;
  const float f1 = tanh_f(r[j]);
  const float f2 = tanh_f(r[512 + j]);
  const float z = sigm_f(r[1024 + j]);
  const float I = z * f1 + (1.f - z) * f2;
  Ichar[(long)b * 512 + j] = f2bf(I);
  Char_out[((long)b * 26 + s) * 512 + j] = I;
}

// ---------------- LSTM cell update ----------------
__global__ void lstm_step_k(const float* __restrict__ gates, float* __restrict__ cbuf,
                            float* __restrict__ hid_out, unsigned short* __restrict__ hall,
                            unsigned short* __restrict__ hprev, int s) {
  const int idx = blockIdx.x * 256 + threadIdx.x;  // B*H
  const int b = idx >> 9, j = idx & 511;
  const float* g = gates + (long)b * 2048;
  const float ig = sigm_f(g[j]);
  const float fg = sigm_f(g[512 + j]);
  const float gg = tanh_f(g[1024 + j]);
  const float og = sigm_f(g[1536 + j]);
  const float cn = fg * cbuf[idx] + ig * gg;
  cbuf[idx] = cn;
  const float hn = og * tanh_f(cn);
  hid_out[((long)b * 26 + s) * 512 + j] = hn;
  const unsigned short hb = f2bf(hn);
  hall[((long)b * 26 + s) * 512 + j] = hb;
  hprev[idx] = hb;
}

// ---------------- prologue helpers ----------------
__global__ void cvt_f32_bf16_k(const float* __restrict__ in, unsigned short* __restrict__ out, long n) {
  const long i = ((long)blockIdx.x * 256 + threadIdx.x) * 4;
  if (i + 4 <= n) {
    const float4 v = *(const float4*)(in + i);
    ushort4 o;
    o.x = f2bf(v.x); o.y = f2bf(v.y); o.z = f2bf(v.z); o.w = f2bf(v.w);
    *(ushort4*)(out + i) = o;
  }
}

__global__ void embed_k(const float* __restrict__ emb_table, const int* __restrict__ text,
                        unsigned short* __restrict__ out) {
  const int bs = blockIdx.x, j = threadIdx.x;  // grid B*NS, block 256
  const int t = text[bs];
  out[(long)bs * 256 + j] = f2bf(emb_table[(long)t * 256 + j]);
}

// WcatA [2560,512] = rows 0..511: W_h2h; rows 512..2559: W_hh
__global__ void pack_A_k(const float* __restrict__ W_h2h, const float* __restrict__ W_hh,
                         unsigned short* __restrict__ out) {
  const long idx = (long)blockIdx.x * 256 + threadIdx.x;  // 2560*512
  const int row = (int)(idx >> 9), k = (int)(idx & 511);
  const float v = (row < 512) ? W_h2h[(long)row * 512 + k] : W_hh[(long)(row - 512) * 512 + k];
  out[idx] = f2bf(v);
}

// Wc [1536,1024]: rows 0..511: [Wf1|0]; 512..1023: [0|Wf2]; 1024..1535: Wz
__global__ void pack_C_k(const float* __restrict__ Wf1, const float* __restrict__ Wf2,
                         const float* __restrict__ Wz, unsigned short* __restrict__ out) {
  const long idx = (long)blockIdx.x * 256 + threadIdx.x;  // 1536*1024
  const int row = (int)(idx >> 10), k = (int)(idx & 1023);
  float v = 0.f;
  if (row < 512)       { if (k < 512)  v = Wf1[(long)row * 512 + k]; }
  else if (row < 1024) { if (k >= 512) v = Wf2[(long)(row - 512) * 512 + (k - 512)]; }
  else                 { v = Wz[(long)(row - 1024) * 1024 + k]; }
  out[idx] = f2bf(v);
}

// Wgen padded to [128,512]
__global__ void pack_Wgen_k(const float* __restrict__ W_gen, unsigned short* __restrict__ out) {
  const long idx = (long)blockIdx.x * 256 + threadIdx.x;  // 128*512
  const int row = (int)(idx >> 9), k = (int)(idx & 511);
  out[idx] = (row < NCLS_) ? f2bf(W_gen[(long)row * 512 + k]) : (unsigned short)0;
}

// biasA [2560] = [b_h2h | b_ih + b_hh]; biasC [1536] = [bf1 | bf2 | bz]
__global__ void pack_bias_k(const float* __restrict__ b_h2h, const float* __restrict__ b_ih,
                            const float* __restrict__ b_hh, const float* __restrict__ bf1,
                            const float* __restrict__ bf2, const float* __restrict__ bz,
                            float* __restrict__ biasA, float* __restrict__ biasC) {
  const int i = blockIdx.x * 256 + threadIdx.x;  // 4096 threads
  if (i < 2560) {
    biasA[i] = (i < 512) ? b_h2h[i] : (b_ih[i - 512] + b_hh[i - 512]);
  } else {
    const int j = i - 2560;
    if (j < 1536) biasC[j] = (j < 512) ? bf1[j] : (j < 1024 ? bf2[j - 512] : bz[j - 1024]);
  }
}

extern "C" void kernel_launch(void* const* d_in, const int* in_sizes, int n_in,
                              void* d_out, int out_size, void* d_ws, size_t ws_size,
                              hipStream_t stream) {
  (void)in_sizes; (void)n_in; (void)out_size; (void)ws_size;
  const float* batch_H  = (const float*)d_in[0];
  const float* AS       = (const float*)d_in[1];
  const int*   text     = (const int*)d_in[2];
  const float* W_i2h    = (const float*)d_in[3];
  const float* W_h2h    = (const float*)d_in[4];
  const float* b_h2h    = (const float*)d_in[5];
  const float* w_score  = (const float*)d_in[6];
  const float* W_ih     = (const float*)d_in[7];
  const float* W_hh     = (const float*)d_in[8];
  const float* b_ih     = (const float*)d_in[9];
  const float* b_hh     = (const float*)d_in[10];
  const float* Wf1      = (const float*)d_in[11];
  const float* bf1      = (const float*)d_in[12];
  const float* Wf2      = (const float*)d_in[13];
  const float* bf2      = (const float*)d_in[14];
  const float* Wz       = (const float*)d_in[15];
  const float* bz       = (const float*)d_in[16];
  const float* W_gen    = (const float*)d_in[17];
  const float* b_gen    = (const float*)d_in[18];
  const float* emb_tab  = (const float*)d_in[19];

  float* out = (float*)d_out;
  float* out_probs = out;                       // [B,NS,NCLS]
  float* out_attn  = out + 1291264;             // [B,T,NS]
  float* out_hid   = out + 2143232;             // [B,NS,H]
  float* out_char  = out + 8958976;             // [B,NS,H]

  char* wsp = (char*)d_ws;
  auto alloc = [&](size_t bytes) { char* p = wsp; wsp += (bytes + 255) & ~(size_t)255; return p; };
  unsigned short* bH      = (unsigned short*)alloc(33554432);  // batch_H bf16 [B,T,C]
  unsigned short* Hproj   = (unsigned short*)alloc(33554432);  // [B,T,H] bf16
  unsigned short* ASb     = (unsigned short*)alloc(13631488);  // [B,NS,H] bf16
  unsigned short* embb    = (unsigned short*)alloc(6815744);   // [B,NS,NEMB] bf16
  unsigned short* Hall    = (unsigned short*)alloc(13631488);  // [B,NS,H] bf16
  unsigned short* WcatA   = (unsigned short*)alloc(2621440);   // [2560,512]
  unsigned short* Wc      = (unsigned short*)alloc(3145728);   // [1536,1024]
  unsigned short* Wihb    = (unsigned short*)alloc(3145728);   // [2048,768]
  unsigned short* Wgenb   = (unsigned short*)alloc(131072);    // [128,512]
  unsigned short* Wi2hb   = (unsigned short*)alloc(524288);    // [512,512]
  float* biasA            = (float*)alloc(10240);              // [2560]
  float* biasC            = (float*)alloc(6144);               // [1536]
  float* hp_gh            = (float*)alloc(5242880);            // [B,2560]
  unsigned short* ctx     = (unsigned short*)alloc(524288);    // [B,512] bf16
  float* fz               = (float*)alloc(3145728);            // [B,1536]
  unsigned short* Ichar   = (unsigned short*)alloc(524288);    // [B,512] bf16
  float* gates            = (float*)alloc(4194304);            // [B,2048]
  float* cbuf             = (float*)alloc(1048576);            // [B,512]
  unsigned short* hprev   = (unsigned short*)alloc(524288);    // [B,512] bf16

  hipMemsetAsync(hprev, 0, 524288, stream);
  hipMemsetAsync(cbuf, 0, 1048576, stream);

  // -------- prologue: conversions / packing --------
  cvt_f32_bf16_k<<<dim3(16384), dim3(256), 0, stream>>>(batch_H, bH, 16777216);
  cvt_f32_bf16_k<<<dim3(6656), dim3(256), 0, stream>>>(AS, ASb, 6815744);
  cvt_f32_bf16_k<<<dim3(1536), dim3(256), 0, stream>>>(W_ih, Wihb, 1572864);
  cvt_f32_bf16_k<<<dim3(256), dim3(256), 0, stream>>>(W_i2h, Wi2hb, 262144);
  embed_k<<<dim3(13312), dim3(256), 0, stream>>>(emb_tab, text, embb);
  pack_A_k<<<dim3(5120), dim3(256), 0, stream>>>(W_h2h, W_hh, WcatA);
  pack_C_k<<<dim3(6144), dim3(256), 0, stream>>>(Wf1, Wf2, Wz, Wc);
  pack_Wgen_k<<<dim3(256), dim3(256), 0, stream>>>(W_gen, Wgenb);
  pack_bias_k<<<dim3(16), dim3(256), 0, stream>>>(b_h2h, b_ih, b_hh, bf1, bf2, bz, biasA, biasC);

  // H_proj = batch_H @ W_i2h^T  (M=32768, N=512, K=512) -> bf16
  gemm_bf16_k<false, true, false, false><<<dim3(8, 512), dim3(256), 0, stream>>>(
      bH, 512, 512, nullptr, 0, Wi2hb, nullptr, nullptr, 0, nullptr, Hproj, 512, 512, 512);

  // -------- 26-step scan --------
  for (int s = 0; s < NS_; ++s) {
    // [hp | gates_h] = h @ [W_h2h^T | W_hh^T] + [b_h2h | b_ih+b_hh]   (M=512,N=2560,K=512)
    gemm_bf16_k<false, false, true, false><<<dim3(40, 8), dim3(256), 0, stream>>>(
        hprev, 512, 512, nullptr, 0, WcatA, biasA, nullptr, 0, hp_gh, nullptr, 2560, 512, 2560);
    // attention: e -> softmax -> context
    attn_step_k<<<dim3(512), dim3(256), 0, stream>>>(Hproj, bH, hp_gh, w_score, out_attn, ctx, s);
    // [f1p | f2p | zp] = [ctx | seq_t] @ Wc^T + biasC   (M=512,N=1536,K=1024)
    gemm_bf16_k<true, false, true, false><<<dim3(24, 8), dim3(256), 0, stream>>>(
        ctx, 512, 512, ASb + (long)s * 512, 26 * 512, Wc, biasC, nullptr, 0, fz, nullptr, 1536, 1024, 1536);
    ichar_step_k<<<dim3(1024), dim3(256), 0, stream>>>(fz, Ichar, out_char, s);
    // gates = [I_char | emb_t] @ W_ih^T + gates_h   (M=512,N=2048,K=768)
    gemm_bf16_k<true, false, false, true><<<dim3(32, 8), dim3(256), 0, stream>>>(
        Ichar, 512, 512, embb + (long)s * 256, 26 * 256, Wihb, nullptr, hp_gh + 512, 2560,
        gates, nullptr, 2048, 768, 2048);
    lstm_step_k<<<dim3(1024), dim3(256), 0, stream>>>(gates, cbuf, out_hid, Hall, hprev, s);
  }

  // probs = H_all @ W_gen^T + b_gen   (M=13312, N=128 padded, K=512, Nvalid=97)
  gemm_bf16_k<false, false, true, false><<<dim3(2, 208), dim3(256), 0, stream>>>(
      Hall, 512, 512, nullptr, 0, Wgenb, b_gen, nullptr, 0, out_probs, nullptr, 97, 512, 97);
}